// Round 13
// baseline (167.859 us; speedup 1.0000x reference)
//
#include <hip/hip_runtime.h>
#include <hip/hip_bf16.h>

typedef __bf16 bf16x8 __attribute__((ext_vector_type(8)));
typedef __bf16 bf16x4 __attribute__((ext_vector_type(4)));
typedef float f32x4 __attribute__((ext_vector_type(4)));
typedef float f32x16 __attribute__((ext_vector_type(16)));

#define NROW 3072
#define NF 512            // IN_F == H*D == 512
#define NH 8
#define ND 64

// Order-preserving float<->uint key for atomicMax over signed floats.
__device__ __forceinline__ unsigned enc_key(float f) {
    unsigned u = __float_as_uint(f);
    return (f < 0.f) ? ~u : (u | 0x80000000u);
}
__device__ __forceinline__ float dec_key(unsigned k) {
    unsigned u = (k & 0x80000000u) ? (k ^ 0x80000000u) : ~k;
    return __uint_as_float(u);
}
__device__ __forceinline__ unsigned short bf16_bits(__bf16 v) {
    return __builtin_bit_cast(unsigned short, v);
}

// ---------------------------------------------------------------------------
// Kernel 0 (merged prep): blocks 0..1791 convert x,W fp32->bf16 (float4);
// blocks 1792..4863 bitpack (adj>0 || j==i) into bits[3072][96] (1.18 MB).
// ---------------------------------------------------------------------------
__global__ __launch_bounds__(256) void k_prep(const float* __restrict__ x,
                                              const float* __restrict__ W,
                                              const int* __restrict__ adj,
                                              __bf16* __restrict__ xb,
                                              __bf16* __restrict__ Wb,
                                              unsigned long long* __restrict__ bits64,
                                              unsigned* __restrict__ maxkey) {
    if (blockIdx.x == 0 && threadIdx.x < NH) maxkey[threadIdx.x] = 0u;
    if (blockIdx.x < 1792) {
        int k = blockIdx.x * 256 + threadIdx.x;
        const float4* s; __bf16* d;
        if (k < 393216) { s = (const float4*)x; d = xb; }
        else { k -= 393216;  s = (const float4*)W; d = Wb; }
        float4 v = s[k];
        bf16x4 o = { (__bf16)v.x, (__bf16)v.y, (__bf16)v.z, (__bf16)v.w };
        *reinterpret_cast<bf16x4*>(d + k * 4) = o;
    } else {
        int i = blockIdx.x - 1792;
        int wave = threadIdx.x >> 6, lane = threadIdx.x & 63;
        const int* row = adj + i * NROW;
#pragma unroll
        for (int it = 0; it < 12; ++it) {
            int base = wave * 768 + it * 64;
            int j = base + lane;
            bool pred = (row[j] > 0) || (j == i);
            unsigned long long bal = __ballot(pred);
            if (lane == 0) bits64[i * 48 + (base >> 6)] = bal;
        }
    }
}

// ---------------------------------------------------------------------------
// Kernel 1: h = x @ W^T (both bf16); write hT only (per-head d-major) via
// LDS transpose. 1536 blocks x 4 wave-tiles (16x16).
// ---------------------------------------------------------------------------
__global__ __launch_bounds__(256) void k_gemm(const __bf16* __restrict__ xb,
                                              const __bf16* __restrict__ Wb,
                                              __bf16* __restrict__ hT) {
    __shared__ __bf16 tile[4][16][17];
    int wave = threadIdx.x >> 6;
    int lane = threadIdx.x & 63;
    int t = blockIdx.x * 4 + wave;          // 6144 tiles: 192 i-tiles x 32 o-tiles
    int i0 = (t >> 5) << 4;
    int o0 = (t & 31) << 4;
    int fr = lane & 15;
    int quad = lane >> 4;

    const bf16x8* xa = reinterpret_cast<const bf16x8*>(xb + (i0 + fr) * NF + quad * 8);
    const bf16x8* wp = reinterpret_cast<const bf16x8*>(Wb + (o0 + fr) * NF + quad * 8);

    f32x4 acc = {0.f, 0.f, 0.f, 0.f};
#pragma unroll
    for (int k = 0; k < 16; ++k) {
        bf16x8 a = xa[k * 4];
        bf16x8 b = wp[k * 4];
        acc = __builtin_amdgcn_mfma_f32_16x16x32_bf16(a, b, acc, 0, 0, 0);
    }
#pragma unroll
    for (int r = 0; r < 4; ++r)
        tile[wave][quad * 4 + r][fr] = (__bf16)acc[r];
    __syncthreads();
    int orow = lane >> 2;
    int li = (lane & 3) * 4;
    bf16x4 o4 = { tile[wave][li][orow], tile[wave][li + 1][orow],
                  tile[wave][li + 2][orow], tile[wave][li + 3][orow] };
    *reinterpret_cast<bf16x4*>(hT + (o0 + orow) * NROW + i0 + li) = o4;
}

// ---------------------------------------------------------------------------
// Kernel 2: e_srcT[h][i], e_dstT[h][i] from hT (coalesced row reads) + fused
// per-head global max. Grid dim3(12, 8).
// ---------------------------------------------------------------------------
__global__ __launch_bounds__(256) void k_edgesT(const __bf16* __restrict__ hT,
                                                const float* __restrict__ a_src,
                                                const float* __restrict__ a_dst,
                                                float* __restrict__ e_srcT,
                                                float* __restrict__ e_dstT,
                                                unsigned* __restrict__ maxkey) {
    int hh = blockIdx.y;
    int i = blockIdx.x * 256 + threadIdx.x;
    float ps = 0.f, pd = 0.f;
#pragma unroll
    for (int d = 0; d < ND; ++d) {
        float hv = (float)hT[(hh * ND + d) * NROW + i];
        ps += hv * a_src[hh * ND + d];
        pd += hv * a_dst[hh * ND + d];
    }
    e_srcT[hh * NROW + i] = ps;
    e_dstT[hh * NROW + i] = pd;
    float mx = pd;
#pragma unroll
    for (int off = 1; off < 64; off <<= 1) mx = fmaxf(mx, __shfl_xor(mx, off, 64));
    if ((threadIdx.x & 63) == 0) atomicMax(&maxkey[hh], enc_key(mx));
}

// ---------------------------------------------------------------------------
// Kernel 3: masked softmax-PV with 32x32x16 MFMA. Block = 4 waves x 32
// i-rows = 128 i; each wave does full d=64 (2 MFMAs/16-j step); p computed
// once per (i,j). A-frag: A[m=lane&31][k=(lane>>5)*8+r]; B symmetric; C/D:
// col=lane&31, row=(reg&3)+8*(reg>>2)+4*(lane>>5).  PQ packed bf16-pairs in
// LDS (uint); den = per-lane fp32 sum of bf16 af (lane owns one row).
// LDS-staged 64-j hT chunks, double-buffered, frag-ordered, conflict-free.
// Grid: 24 i-blocks x 4 jc x 8 heads = 768 blocks, 256 thr, 19 KB LDS.
// num written bf16 (halves round-trip).
// ---------------------------------------------------------------------------
__global__ __launch_bounds__(256) void k_attn(const unsigned* __restrict__ bits,
                                              const float* __restrict__ e_srcT,
                                              const float* __restrict__ e_dstT,
                                              const unsigned* __restrict__ maxkey,
                                              const __bf16* __restrict__ hT,
                                              __bf16* __restrict__ num,
                                              float* __restrict__ den) {
    constexpr int JCHUNK = NROW / 4;         // 768
    constexpr int NC = JCHUNK / 64;          // 12 chunks of 64 j
    __shared__ unsigned lds_pq[JCHUNK];                  // 3 KB (P lo16, Q hi16)
    __shared__ __align__(16) __bf16 hbuf[2][4096];       // 2 x 8 KB
    int b = blockIdx.x;
    int head = b & 7;
    int jc = (b >> 3) & 3;
    int i0 = ((b >> 3) >> 2) * 128;
    int jbase = jc * JCHUNK;
    int tid = threadIdx.x;
    int wave = tid >> 6, lane = tid & 63;
    int half = lane >> 5, l31 = lane & 31;

    float Mg = dec_key(maxkey[head]);
    for (int j = tid; j < JCHUNK; j += 256) {
        float t = e_dstT[head * NROW + jbase + j] - Mg;   // <= 0
        __bf16 pb = (__bf16)__expf(t);
        __bf16 qb = (__bf16)__expf(0.2f * t);
        lds_pq[j] = (unsigned)bf16_bits(pb) | ((unsigned)bf16_bits(qb) << 16);
    }

    int irow = i0 + wave * 32 + l31;
    float u = e_srcT[head * NROW + irow] + Mg;
    float A = (u > 0.f) ? 1.f : __expf(0.8f * u);
    float C = (u > 0.f) ? __expf(-0.8f * u) : 1.f;
    float T = __expf(-u);
    const unsigned* brow = bits + irow * 96 + jc * (JCHUNK / 32);

    // staging: 512 slots of 16 B; slot s: js=s>>7, dh=(s>>6)&1, sl=s&63;
    // contents: V[j=jbase+kc*64+js*16+((sl>>5)&1)*8 + r][d=dh*32+(sl&31)]
    // thread t stages slots t and t+256.
    const __bf16* gp0;
    const __bf16* gp1;
    {
        int s = tid;
        gp0 = hT + (head * ND + ((s >> 6) & 1) * 32 + (s & 31)) * NROW
                 + jbase + (s >> 7) * 16 + ((s >> 5) & 1) * 8;
        s = tid + 256;
        gp1 = hT + (head * ND + ((s >> 6) & 1) * 32 + (s & 31)) * NROW
                 + jbase + (s >> 7) * 16 + ((s >> 5) & 1) * 8;
    }
    *reinterpret_cast<bf16x8*>(&hbuf[0][tid * 8])         = *reinterpret_cast<const bf16x8*>(gp0);
    *reinterpret_cast<bf16x8*>(&hbuf[0][(tid + 256) * 8]) = *reinterpret_cast<const bf16x8*>(gp1);
    __syncthreads();

    f32x16 acc0 = {}, acc1 = {};
    float lsum = 0.f;
    uint2 wm = *reinterpret_cast<const uint2*>(brow);

    for (int k = 0; k < NC; ++k) {
        bf16x8 st0, st1;
        uint2 wmn = wm;
        bool more = (k + 1 < NC);
        if (more) {
            st0 = *reinterpret_cast<const bf16x8*>(gp0 + (k + 1) * 64);
            st1 = *reinterpret_cast<const bf16x8*>(gp1 + (k + 1) * 64);
            wmn = *reinterpret_cast<const uint2*>(brow + (k + 1) * 2);
        }
        const __bf16* hb = &hbuf[k & 1][0];
#pragma unroll
        for (int js = 0; js < 4; ++js) {
            unsigned word = (js < 2) ? wm.x : wm.y;
            unsigned w8 = (word >> ((js & 1) * 16 + half * 8)) & 0xffu;
            const uint4* pp = reinterpret_cast<const uint4*>(&lds_pq[k * 64 + js * 16 + half * 8]);
            uint4 pq0 = pp[0], pq1 = pp[1];
            unsigned pr[8] = {pq0.x, pq0.y, pq0.z, pq0.w, pq1.x, pq1.y, pq1.z, pq1.w};
            bf16x8 af;
#pragma unroll
            for (int t = 0; t < 8; ++t) {
                float Pf = __uint_as_float(pr[t] << 16);
                float Qf = __uint_as_float(pr[t] & 0xFFFF0000u);
                bool pos = Pf > T;
                float p = (pos ? Pf : Qf) * (pos ? A : C);
                __bf16 pb = ((w8 >> t) & 1u) ? (__bf16)p : (__bf16)0.f;
                af[t] = pb;
                lsum += (float)pb;
            }
            bf16x8 v0 = *reinterpret_cast<const bf16x8*>(hb + (js * 128 + 0 * 64 + lane) * 8);
            bf16x8 v1 = *reinterpret_cast<const bf16x8*>(hb + (js * 128 + 1 * 64 + lane) * 8);
            acc0 = __builtin_amdgcn_mfma_f32_32x32x16_bf16(af, v0, acc0, 0, 0, 0);
            acc1 = __builtin_amdgcn_mfma_f32_32x32x16_bf16(af, v1, acc1, 0, 0, 0);
        }
        if (more) {
            *reinterpret_cast<bf16x8*>(&hbuf[(k + 1) & 1][tid * 8])         = st0;
            *reinterpret_cast<bf16x8*>(&hbuf[(k + 1) & 1][(tid + 256) * 8]) = st1;
        }
        wm = wmn;
        __syncthreads();
    }

    // den: lane owns row irow (halves hold partial sums over their k-halves)
    lsum += __shfl_xor(lsum, 32, 64);
    if (half == 0)
        den[(jc * NROW + irow) * NH + head] = lsum;

    // num (bf16): C/D col = d = dh*32 + l31; row = (reg&3)+8*(reg>>2)+4*half
#pragma unroll
    for (int reg = 0; reg < 16; ++reg) {
        int rowl = (reg & 3) + 8 * (reg >> 2) + 4 * half;
        long ob = (long)(jc * NROW + i0 + wave * 32 + rowl) * NF + head * ND + l31;
        num[ob]      = (__bf16)acc0[reg];
        num[ob + 32] = (__bf16)acc1[reg];
    }
}

// ---------------------------------------------------------------------------
// Kernel 4: out[i,c] = sum_jc num[jc][i][c] / sum_jc den[jc][i][c>>6]
// ---------------------------------------------------------------------------
__global__ __launch_bounds__(256) void k_reduce(const __bf16* __restrict__ num,
                                                const float* __restrict__ den,
                                                float* __restrict__ out) {
    int idx = blockIdx.x * 256 + threadIdx.x;     // 0 .. NROW*NF
    int i = idx >> 9;
    int c = idx & 511;
    int head = c >> 6;
    float ns = (float)num[(long)i * NF + c] + (float)num[(long)(NROW + i) * NF + c]
             + (float)num[(long)(2 * NROW + i) * NF + c] + (float)num[(long)(3 * NROW + i) * NF + c];
    float ds = den[i * NH + head] + den[(NROW + i) * NH + head]
             + den[(2 * NROW + i) * NH + head] + den[(3 * NROW + i) * NH + head];
    out[idx] = ns / fmaxf(ds, 1e-30f);
}

// ---------------------------------------------------------------------------
extern "C" void kernel_launch(void* const* d_in, const int* in_sizes, int n_in,
                              void* d_out, int out_size, void* d_ws, size_t ws_size,
                              hipStream_t stream) {
    const float* x_raw  = (const float*)d_in[0];
    const int*   adj    = (const int*)d_in[1];
    const float* W_raw  = (const float*)d_in[2];
    const float* as_raw = (const float*)d_in[3];
    const float* ad_raw = (const float*)d_in[4];
    float* out = (float*)d_out;

    char* ws = (char*)d_ws;
    __bf16*   hT     = (__bf16*)(ws);                    // 3,145,728 B
    float*    e_srcT = (float*)(ws + 3145728);           //    98,304 B
    float*    e_dstT = (float*)(ws + 3244032);           //    98,304 B
    unsigned* maxkey = (unsigned*)(ws + 3342336);        //        64 B
    unsigned* bits   = (unsigned*)(ws + 3342400);        // 1,179,648 B
    __bf16*   xb     = (__bf16*)(ws + 4522048);          // 3,145,728 B
    __bf16*   Wb     = (__bf16*)(ws + 7667776);          //   524,288 B
    __bf16*   num    = (__bf16*)(ws + 8192064);          // 12,582,912 B (bf16)
    float*    den    = (float*)(ws + 20774976);          //   393,216 B
    // total 21,168,192 B (<= previously-verified capacity)

    k_prep<<<4864, 256, 0, stream>>>(x_raw, W_raw, adj, xb, Wb,
                                     (unsigned long long*)bits, maxkey);
    k_gemm<<<1536, 256, 0, stream>>>(xb, Wb, hT);
    k_edgesT<<<dim3(12, 8), 256, 0, stream>>>(hT, as_raw, ad_raw, e_srcT, e_dstT, maxkey);
    k_attn<<<24 * 4 * 8, 256, 0, stream>>>(bits, e_srcT, e_dstT, maxkey, hT, num, den);
    k_reduce<<<NROW * NF / 256, 256, 0, stream>>>(num, den, out);
}

// Round 16
// 160.943 us; speedup vs baseline: 1.0430x; 1.0430x over previous
//
#include <hip/hip_runtime.h>
#include <hip/hip_bf16.h>

typedef __bf16 bf16x8 __attribute__((ext_vector_type(8)));
typedef __bf16 bf16x4 __attribute__((ext_vector_type(4)));
typedef float f32x4 __attribute__((ext_vector_type(4)));
typedef float f32x16 __attribute__((ext_vector_type(16)));

#define NROW 3072
#define NF 512            // IN_F == H*D == 512
#define NH 8
#define ND 64

// Order-preserving float<->uint key for atomicMax over signed floats.
__device__ __forceinline__ unsigned gat_enc_key(float f) {
    unsigned u = __float_as_uint(f);
    return (f < 0.f) ? ~u : (u | 0x80000000u);
}
__device__ __forceinline__ float gat_dec_key(unsigned k) {
    unsigned u = (k & 0x80000000u) ? (k ^ 0x80000000u) : ~k;
    return __uint_as_float(u);
}
__device__ __forceinline__ unsigned short gat_bf16_bits(__bf16 v) {
    return __builtin_bit_cast(unsigned short, v);
}

// ---------------------------------------------------------------------------
// Stage 0 (merged prep): blocks 0..1791 convert x,W fp32->bf16 (float4);
// blocks 1792..4863 bitpack (adj>0 || j==i) into bits[3072][96] (1.18 MB).
// ---------------------------------------------------------------------------
__global__ __launch_bounds__(256) void gat_prep(const float* __restrict__ x,
                                                const float* __restrict__ W,
                                                const int* __restrict__ adj,
                                                __bf16* __restrict__ xb,
                                                __bf16* __restrict__ Wb,
                                                unsigned long long* __restrict__ bits64,
                                                unsigned* __restrict__ maxkey) {
    if (blockIdx.x == 0 && threadIdx.x < NH) maxkey[threadIdx.x] = 0u;
    if (blockIdx.x < 1792) {
        int k = blockIdx.x * 256 + threadIdx.x;
        const float4* s; __bf16* d;
        if (k < 393216) { s = (const float4*)x; d = xb; }
        else { k -= 393216;  s = (const float4*)W; d = Wb; }
        float4 v = s[k];
        bf16x4 o = { (__bf16)v.x, (__bf16)v.y, (__bf16)v.z, (__bf16)v.w };
        *reinterpret_cast<bf16x4*>(d + k * 4) = o;
    } else {
        int i = blockIdx.x - 1792;
        int wave = threadIdx.x >> 6;
        int lane = threadIdx.x & 63;
        const int* row = adj + i * NROW;
#pragma unroll
        for (int it = 0; it < 12; ++it) {
            int base = wave * 768 + it * 64;
            int j = base + lane;
            bool pred = (row[j] > 0) || (j == i);
            unsigned long long bal = __ballot(pred);
            if (lane == 0) bits64[i * 48 + (base >> 6)] = bal;
        }
    }
}

// ---------------------------------------------------------------------------
// Stage 1: h = x @ W^T (both bf16); write hT only (per-head d-major) via
// LDS transpose. 1536 blocks x 4 wave-tiles (16x16).
// ---------------------------------------------------------------------------
__global__ __launch_bounds__(256) void gat_gemm(const __bf16* __restrict__ xb,
                                                const __bf16* __restrict__ Wb,
                                                __bf16* __restrict__ hT) {
    __shared__ __bf16 tile[4][16][17];
    int wave = threadIdx.x >> 6;
    int lane = threadIdx.x & 63;
    int t = blockIdx.x * 4 + wave;          // 6144 tiles: 192 i-tiles x 32 o-tiles
    int i0 = (t >> 5) << 4;
    int o0 = (t & 31) << 4;
    int fr = lane & 15;
    int quad = lane >> 4;

    const bf16x8* xa = reinterpret_cast<const bf16x8*>(xb + (i0 + fr) * NF + quad * 8);
    const bf16x8* wp = reinterpret_cast<const bf16x8*>(Wb + (o0 + fr) * NF + quad * 8);

    f32x4 acc = {0.f, 0.f, 0.f, 0.f};
#pragma unroll
    for (int k = 0; k < 16; ++k) {
        bf16x8 a = xa[k * 4];
        bf16x8 b = wp[k * 4];
        acc = __builtin_amdgcn_mfma_f32_16x16x32_bf16(a, b, acc, 0, 0, 0);
    }
#pragma unroll
    for (int r = 0; r < 4; ++r)
        tile[wave][quad * 4 + r][fr] = (__bf16)acc[r];
    __syncthreads();
    int orow = lane >> 2;
    int li = (lane & 3) * 4;
    bf16x4 o4 = { tile[wave][li][orow], tile[wave][li + 1][orow],
                  tile[wave][li + 2][orow], tile[wave][li + 3][orow] };
    *reinterpret_cast<bf16x4*>(hT + (o0 + orow) * NROW + i0 + li) = o4;
}

// ---------------------------------------------------------------------------
// Stage 2: e_srcT[h][i], e_dstT[h][i] from hT (coalesced row reads) + fused
// per-head global max. Grid dim3(12, 8).
// ---------------------------------------------------------------------------
__global__ __launch_bounds__(256) void gat_edges(const __bf16* __restrict__ hT,
                                                 const float* __restrict__ a_src,
                                                 const float* __restrict__ a_dst,
                                                 float* __restrict__ e_srcT,
                                                 float* __restrict__ e_dstT,
                                                 unsigned* __restrict__ maxkey) {
    int hh = blockIdx.y;
    int i = blockIdx.x * 256 + threadIdx.x;
    float ps = 0.f, pd = 0.f;
#pragma unroll
    for (int d = 0; d < ND; ++d) {
        float hv = (float)hT[(hh * ND + d) * NROW + i];
        ps += hv * a_src[hh * ND + d];
        pd += hv * a_dst[hh * ND + d];
    }
    e_srcT[hh * NROW + i] = ps;
    e_dstT[hh * NROW + i] = pd;
    float mx = pd;
#pragma unroll
    for (int off = 1; off < 64; off <<= 1) mx = fmaxf(mx, __shfl_xor(mx, off, 64));
    if ((threadIdx.x & 63) == 0) atomicMax(&maxkey[hh], gat_enc_key(mx));
}

// ---------------------------------------------------------------------------
// Stage 3: masked softmax-PV with 32x32x16 MFMA (halves LDS reads vs 16x16).
// Block = 4 waves x 32 i-rows = 128 i; each wave full d=64; p computed once
// per (i,j). PQ packed bf16-pairs in LDS (uint); den = per-lane fp32 sum.
// LDS-staged 64-j hT chunks, double-buffered, frag-ordered, conflict-free.
// Grid: 24 i-blocks x 4 jc x 8 heads = 768 blocks, 256 thr, 19 KB LDS.
// num written bf16 (halves round-trip).
// ---------------------------------------------------------------------------
__global__ __launch_bounds__(256) void gat_attn(const unsigned* __restrict__ bits,
                                                const float* __restrict__ e_srcT,
                                                const float* __restrict__ e_dstT,
                                                const unsigned* __restrict__ maxkey,
                                                const __bf16* __restrict__ hT,
                                                __bf16* __restrict__ num,
                                                float* __restrict__ den) {
    constexpr int JCHUNK = NROW / 4;         // 768
    constexpr int NC = JCHUNK / 64;          // 12 chunks of 64 j
    __shared__ unsigned lds_pq[JCHUNK];                  // 3 KB (P lo16, Q hi16)
    __shared__ __align__(16) __bf16 hbuf[2][4096];       // 2 x 8 KB
    int b = blockIdx.x;
    int head = b & 7;
    int jc = (b >> 3) & 3;
    int i0 = ((b >> 3) >> 2) * 128;
    int jbase = jc * JCHUNK;
    int tid = threadIdx.x;
    int wave = tid >> 6;
    int lane = tid & 63;
    int half = lane >> 5;
    int l31 = lane & 31;

    float Mg = gat_dec_key(maxkey[head]);
    for (int j = tid; j < JCHUNK; j += 256) {
        float t = e_dstT[head * NROW + jbase + j] - Mg;   // <= 0
        __bf16 pb = (__bf16)__expf(t);
        __bf16 qb = (__bf16)__expf(0.2f * t);
        lds_pq[j] = (unsigned)gat_bf16_bits(pb) | ((unsigned)gat_bf16_bits(qb) << 16);
    }

    int irow = i0 + wave * 32 + l31;
    float u = e_srcT[head * NROW + irow] + Mg;
    float A = (u > 0.f) ? 1.f : __expf(0.8f * u);
    float C = (u > 0.f) ? __expf(-0.8f * u) : 1.f;
    float T = __expf(-u);
    const unsigned* brow = bits + irow * 96 + jc * (JCHUNK / 32);

    // staging: 512 slots of 16 B; slot s: js=s>>7, dh=(s>>6)&1, sl=s&63;
    // thread t stages slots t and t+256.
    int s0 = tid, s1 = tid + 256;
    const __bf16* gp0 = hT + (head * ND + ((s0 >> 6) & 1) * 32 + (s0 & 31)) * NROW
                           + jbase + (s0 >> 7) * 16 + ((s0 >> 5) & 1) * 8;
    const __bf16* gp1 = hT + (head * ND + ((s1 >> 6) & 1) * 32 + (s1 & 31)) * NROW
                           + jbase + (s1 >> 7) * 16 + ((s1 >> 5) & 1) * 8;
    *reinterpret_cast<bf16x8*>(&hbuf[0][tid * 8])         = *reinterpret_cast<const bf16x8*>(gp0);
    *reinterpret_cast<bf16x8*>(&hbuf[0][(tid + 256) * 8]) = *reinterpret_cast<const bf16x8*>(gp1);
    __syncthreads();

    f32x16 acc0 = {};
    f32x16 acc1 = {};
    float lsum = 0.f;
    uint2 wm = *reinterpret_cast<const uint2*>(brow);

    for (int k = 0; k < NC; ++k) {
        bf16x8 st0, st1;
        uint2 wmn = wm;
        bool more = (k + 1 < NC);
        if (more) {
            st0 = *reinterpret_cast<const bf16x8*>(gp0 + (k + 1) * 64);
            st1 = *reinterpret_cast<const bf16x8*>(gp1 + (k + 1) * 64);
            wmn = *reinterpret_cast<const uint2*>(brow + (k + 1) * 2);
        }
        const __bf16* hb = &hbuf[k & 1][0];
#pragma unroll
        for (int js = 0; js < 4; ++js) {
            unsigned word = (js < 2) ? wm.x : wm.y;
            unsigned w8 = (word >> ((js & 1) * 16 + half * 8)) & 0xffu;
            const uint4* pp = reinterpret_cast<const uint4*>(&lds_pq[k * 64 + js * 16 + half * 8]);
            uint4 pq0 = pp[0], pq1 = pp[1];
            unsigned pr[8] = {pq0.x, pq0.y, pq0.z, pq0.w, pq1.x, pq1.y, pq1.z, pq1.w};
            bf16x8 af;
#pragma unroll
            for (int t = 0; t < 8; ++t) {
                float Pf = __uint_as_float(pr[t] << 16);
                float Qf = __uint_as_float(pr[t] & 0xFFFF0000u);
                bool pos = Pf > T;
                float p = (pos ? Pf : Qf) * (pos ? A : C);
                __bf16 pb = ((w8 >> t) & 1u) ? (__bf16)p : (__bf16)0.f;
                af[t] = pb;
                lsum += (float)pb;
            }
            bf16x8 v0 = *reinterpret_cast<const bf16x8*>(hb + (js * 128 + lane) * 8);
            bf16x8 v1 = *reinterpret_cast<const bf16x8*>(hb + (js * 128 + 64 + lane) * 8);
            acc0 = __builtin_amdgcn_mfma_f32_32x32x16_bf16(af, v0, acc0, 0, 0, 0);
            acc1 = __builtin_amdgcn_mfma_f32_32x32x16_bf16(af, v1, acc1, 0, 0, 0);
        }
        if (more) {
            *reinterpret_cast<bf16x8*>(&hbuf[(k + 1) & 1][tid * 8])         = st0;
            *reinterpret_cast<bf16x8*>(&hbuf[(k + 1) & 1][(tid + 256) * 8]) = st1;
        }
        wm = wmn;
        __syncthreads();
    }

    // den: lane owns row irow (halves hold partial sums over their k-halves)
    lsum += __shfl_xor(lsum, 32, 64);
    if (half == 0)
        den[(jc * NROW + irow) * NH + head] = lsum;

    // num (bf16): C/D col = d = dh*32 + l31; row = (reg&3)+8*(reg>>2)+4*half
#pragma unroll
    for (int reg = 0; reg < 16; ++reg) {
        int rowl = (reg & 3) + 8 * (reg >> 2) + 4 * half;
        long ob = (long)(jc * NROW + i0 + wave * 32 + rowl) * NF + head * ND + l31;
        num[ob]      = (__bf16)acc0[reg];
        num[ob + 32] = (__bf16)acc1[reg];
    }
}

// ---------------------------------------------------------------------------
// Stage 4: out[i,c..c+7] = sum_jc num[jc][i][c..] / sum_jc den[jc][i][c>>6]
// Vectorized: one thread = 8 consecutive c (bf16x8 loads, float4 stores).
// Grid 768 x 256.
// ---------------------------------------------------------------------------
__global__ __launch_bounds__(256) void gat_final(const __bf16* __restrict__ num,
                                                 const float* __restrict__ den,
                                                 float* __restrict__ out) {
    int idx = (blockIdx.x * 256 + threadIdx.x) * 8;   // 0 .. NROW*NF step 8
    int i = idx >> 9;
    int c = idx & 511;
    int head = c >> 6;
    bf16x8 n0 = *reinterpret_cast<const bf16x8*>(num + (long)i * NF + c);
    bf16x8 n1 = *reinterpret_cast<const bf16x8*>(num + (long)(NROW + i) * NF + c);
    bf16x8 n2 = *reinterpret_cast<const bf16x8*>(num + (long)(2 * NROW + i) * NF + c);
    bf16x8 n3 = *reinterpret_cast<const bf16x8*>(num + (long)(3 * NROW + i) * NF + c);
    float ds = den[i * NH + head] + den[(NROW + i) * NH + head]
             + den[(2 * NROW + i) * NH + head] + den[(3 * NROW + i) * NH + head];
    float inv = 1.0f / fmaxf(ds, 1e-30f);
    float r0 = ((float)n0[0] + (float)n1[0] + (float)n2[0] + (float)n3[0]) * inv;
    float r1 = ((float)n0[1] + (float)n1[1] + (float)n2[1] + (float)n3[1]) * inv;
    float r2 = ((float)n0[2] + (float)n1[2] + (float)n2[2] + (float)n3[2]) * inv;
    float r3 = ((float)n0[3] + (float)n1[3] + (float)n2[3] + (float)n3[3]) * inv;
    float r4 = ((float)n0[4] + (float)n1[4] + (float)n2[4] + (float)n3[4]) * inv;
    float r5 = ((float)n0[5] + (float)n1[5] + (float)n2[5] + (float)n3[5]) * inv;
    float r6 = ((float)n0[6] + (float)n1[6] + (float)n2[6] + (float)n3[6]) * inv;
    float r7 = ((float)n0[7] + (float)n1[7] + (float)n2[7] + (float)n3[7]) * inv;
    float4 o0 = { r0, r1, r2, r3 };
    float4 o1 = { r4, r5, r6, r7 };
    *reinterpret_cast<float4*>(out + idx)     = o0;
    *reinterpret_cast<float4*>(out + idx + 4) = o1;
}

// ---------------------------------------------------------------------------
extern "C" void kernel_launch(void* const* d_in, const int* in_sizes, int n_in,
                              void* d_out, int out_size, void* d_ws, size_t ws_size,
                              hipStream_t stream) {
    const float* x_raw  = (const float*)d_in[0];
    const int*   adj    = (const int*)d_in[1];
    const float* W_raw  = (const float*)d_in[2];
    const float* as_raw = (const float*)d_in[3];
    const float* ad_raw = (const float*)d_in[4];
    float* out = (float*)d_out;

    char* ws = (char*)d_ws;
    __bf16*   hT     = (__bf16*)(ws);                    // 3,145,728 B
    float*    e_srcT = (float*)(ws + 3145728);           //    98,304 B
    float*    e_dstT = (float*)(ws + 3244032);           //    98,304 B
    unsigned* maxkey = (unsigned*)(ws + 3342336);        //        64 B
    unsigned* bits   = (unsigned*)(ws + 3342400);        // 1,179,648 B
    __bf16*   xb     = (__bf16*)(ws + 4522048);          // 3,145,728 B
    __bf16*   Wb     = (__bf16*)(ws + 7667776);          //   524,288 B
    __bf16*   num    = (__bf16*)(ws + 8192064);          // 12,582,912 B (bf16)
    float*    den    = (float*)(ws + 20774976);          //   393,216 B
    // total 21,168,192 B (<= previously-verified capacity)

    gat_prep<<<4864, 256, 0, stream>>>(x_raw, W_raw, adj, xb, Wb,
                                       (unsigned long long*)bits, maxkey);
    gat_gemm<<<1536, 256, 0, stream>>>(xb, Wb, hT);
    gat_edges<<<dim3(12, 8), 256, 0, stream>>>(hT, as_raw, ad_raw, e_srcT, e_dstT, maxkey);
    gat_attn<<<24 * 4 * 8, 256, 0, stream>>>(bits, e_srcT, e_dstT, maxkey, hT, num, den);
    gat_final<<<NROW * NF / 2048, 256, 0, stream>>>(num, den, out);
}